// Round 1
// baseline (496.328 us; speedup 1.0000x reference)
//
#include <hip/hip_runtime.h>

#define S_LEN 2048
#define NH 32
#define NKV 8
#define HD 64
#define QH_DIM (NH * HD)   // 2048
#define KV_DIM (NKV * HD)  // 512

typedef __attribute__((ext_vector_type(8))) __bf16 bf16x8;
typedef __attribute__((ext_vector_type(4))) float fx4;

__device__ __forceinline__ unsigned short f2bf(float f) {
  unsigned int u = __builtin_bit_cast(unsigned int, f);
  u = (u + 0x7fffu + ((u >> 16) & 1u)) >> 16;
  return (unsigned short)u;
}
__device__ __forceinline__ float bf2f(unsigned short h) {
  unsigned int u = ((unsigned int)h) << 16;
  return __builtin_bit_cast(float, u);
}
__device__ __forceinline__ fx4 zero4() {
  fx4 z; z[0] = 0.f; z[1] = 0.f; z[2] = 0.f; z[3] = 0.f; return z;
}

#define MFMA16(a, b, c) __builtin_amdgcn_mfma_f32_16x16x32_bf16((a), (b), (c), 0, 0, 0)

// ---------------- cast fp32 -> bf16, vectorized ----------------
__global__ __launch_bounds__(256) void cast_kernel(const float* __restrict__ in,
                                                   unsigned short* __restrict__ out, int n4) {
  int i = blockIdx.x * 256 + threadIdx.x;
  if (i >= n4) return;
  float4 v = ((const float4*)in)[i];
  ushort4 o;
  o.x = f2bf(v.x); o.y = f2bf(v.y); o.z = f2bf(v.z); o.w = f2bf(v.w);
  ((ushort4*)out)[i] = o;
}

// ---------------- RoPE in-place on bf16 [S][nheads*64] ----------------
__global__ __launch_bounds__(256) void rope_kernel(unsigned short* __restrict__ buf,
                                                   const float* __restrict__ cosp,
                                                   const float* __restrict__ sinp, int nheads) {
  int idx = blockIdx.x * 256 + threadIdx.x;
  int total = S_LEN * nheads * 32;
  if (idx >= total) return;
  int dp = idx & 31;
  int t = idx >> 5;
  int head = t % nheads;
  int s = t / nheads;
  size_t base = (size_t)s * nheads * 64 + head * 64;
  float x1 = bf2f(buf[base + dp]);
  float x2 = bf2f(buf[base + dp + 32]);
  float c1 = cosp[s * 64 + dp], s1 = sinp[s * 64 + dp];
  float c2 = cosp[s * 64 + dp + 32], s2 = sinp[s * 64 + dp + 32];
  buf[base + dp] = f2bf(x1 * c1 - x2 * s1);
  buf[base + dp + 32] = f2bf(x2 * c2 + x1 * s2);
}

// ---------------- V [S][512] -> Vt [512][S] ----------------
__global__ __launch_bounds__(256) void transpose_v(const unsigned short* __restrict__ V,
                                                   unsigned short* __restrict__ Vt) {
  int idx = blockIdx.x * 256 + threadIdx.x;  // 512*2048 total
  int c = idx >> 11;                         // 0..511
  int r = idx & 2047;                        // 0..2047
  Vt[((size_t)c << 11) + r] = V[((size_t)r << 9) + c];
}

// ---------------- GEMM: C[M][N] = A[M][K] * B[N][K]^T (bf16 in) ----------------
template <int F32OUT>
__global__ __launch_bounds__(256) void gemm_bt(const unsigned short* __restrict__ A,
                                               const unsigned short* __restrict__ B,
                                               void* __restrict__ C, int M, int N, int K) {
  __shared__ unsigned short As[128 * 32];
  __shared__ unsigned short Bs[128 * 32];
  const int tid = threadIdx.x;
  const int bn = blockIdx.x * 128, bm = blockIdx.y * 128;
  const int lane = tid & 63, wid = tid >> 6;
  const int lo = lane & 15, g = lane >> 4;
  const int wr = wid >> 1, wc = wid & 1;

  fx4 acc[4][4];
#pragma unroll
  for (int i = 0; i < 4; i++)
#pragma unroll
    for (int j = 0; j < 4; j++) acc[i][j] = zero4();

  const int r0 = tid >> 2, sg = tid & 3;
  const unsigned short* ap0 = &A[(size_t)(bm + r0) * K + sg * 8];
  const unsigned short* ap1 = &A[(size_t)(bm + 64 + r0) * K + sg * 8];
  const unsigned short* bp0 = &B[(size_t)(bn + r0) * K + sg * 8];
  const unsigned short* bp1 = &B[(size_t)(bn + 64 + r0) * K + sg * 8];

  for (int k0 = 0; k0 < K; k0 += 32) {
    bf16x8 a0 = *(const bf16x8*)(ap0 + k0);
    bf16x8 a1 = *(const bf16x8*)(ap1 + k0);
    bf16x8 b0 = *(const bf16x8*)(bp0 + k0);
    bf16x8 b1 = *(const bf16x8*)(bp1 + k0);
    __syncthreads();  // previous iteration's LDS reads done
    *(bf16x8*)&As[(size_t)tid * 8] = a0;
    *(bf16x8*)&As[(size_t)tid * 8 + 2048] = a1;
    *(bf16x8*)&Bs[(size_t)tid * 8] = b0;
    *(bf16x8*)&Bs[(size_t)tid * 8 + 2048] = b1;
    __syncthreads();
    bf16x8 af[4], bb[4];
#pragma unroll
    for (int mi = 0; mi < 4; mi++)
      af[mi] = *(const bf16x8*)&As[(wr * 64 + mi * 16 + lo) * 32 + g * 8];
#pragma unroll
    for (int nj = 0; nj < 4; nj++)
      bb[nj] = *(const bf16x8*)&Bs[(wc * 64 + nj * 16 + lo) * 32 + g * 8];
#pragma unroll
    for (int mi = 0; mi < 4; mi++)
#pragma unroll
      for (int nj = 0; nj < 4; nj++) acc[mi][nj] = MFMA16(af[mi], bb[nj], acc[mi][nj]);
  }

#pragma unroll
  for (int mi = 0; mi < 4; mi++)
#pragma unroll
    for (int nj = 0; nj < 4; nj++)
#pragma unroll
      for (int r = 0; r < 4; r++) {
        int row = bm + wr * 64 + mi * 16 + g * 4 + r;
        int col = bn + wc * 64 + nj * 16 + lo;
        if (F32OUT)
          ((float*)C)[(size_t)row * N + col] = acc[mi][nj][r];
        else
          ((unsigned short*)C)[(size_t)row * N + col] = f2bf(acc[mi][nj][r]);
      }
}

// ---------------- fused causal attention ----------------
// grid (NH, 32 qtiles); 4 waves; each wave owns 16 q-rows.
// Two sweeps over k-tiles: (1) online m,l  (2) write P fp32 + PV accumulate.
__global__ __launch_bounds__(256) void attn_kernel(const unsigned short* __restrict__ Q,
                                                   const unsigned short* __restrict__ Kb,
                                                   const unsigned short* __restrict__ Vt,
                                                   float* __restrict__ P,
                                                   unsigned short* __restrict__ AO) {
  __shared__ float pls[4][16][84];  // per-wave P staging; 84-stride: conflict-free
  const int h = blockIdx.x;
  const int qt = 31 - blockIdx.y;  // heavy (large qt) blocks dispatch first
  const int hkv = h >> 2;
  const int wid = threadIdx.x >> 6, lane = threadIdx.x & 63;
  const int lo = lane & 15, g = lane >> 4;
  const int rowb = qt * 64 + wid * 16;

  const bf16x8 qa0 = *(const bf16x8*)&Q[(size_t)(rowb + lo) * QH_DIM + h * HD + g * 8];
  const bf16x8 qa1 = *(const bf16x8*)&Q[(size_t)(rowb + lo) * QH_DIM + h * HD + 32 + g * 8];

  float m[4], l[4];
#pragma unroll
  for (int r = 0; r < 4; r++) { m[r] = -1e30f; l[r] = 0.f; }

  // ---- sweep 1: running max/denominator ----
  for (int kt = 0; kt <= qt; ++kt) {
    fx4 acc[4];
#pragma unroll
    for (int nj = 0; nj < 4; nj++) acc[nj] = zero4();
#pragma unroll
    for (int nj = 0; nj < 4; nj++) {
      const int kcol = kt * 64 + nj * 16 + lo;
      bf16x8 kb0 = *(const bf16x8*)&Kb[(size_t)kcol * KV_DIM + hkv * HD + g * 8];
      bf16x8 kb1 = *(const bf16x8*)&Kb[(size_t)kcol * KV_DIM + hkv * HD + 32 + g * 8];
      acc[nj] = MFMA16(qa0, kb0, acc[nj]);
      acc[nj] = MFMA16(qa1, kb1, acc[nj]);
    }
    float tmax[4];
#pragma unroll
    for (int r = 0; r < 4; r++) tmax[r] = -1e30f;
#pragma unroll
    for (int nj = 0; nj < 4; nj++)
#pragma unroll
      for (int r = 0; r < 4; r++) {
        const int qg = rowb + g * 4 + r;
        const int kg = kt * 64 + nj * 16 + lo;
        float s = acc[nj][r] * 0.125f;
        if (kg > qg) s = -1e9f;
        acc[nj][r] = s;
        tmax[r] = fmaxf(tmax[r], s);
      }
#pragma unroll
    for (int r = 0; r < 4; r++) {
      float t = tmax[r];
      t = fmaxf(t, __shfl_xor(t, 1));
      t = fmaxf(t, __shfl_xor(t, 2));
      t = fmaxf(t, __shfl_xor(t, 4));
      t = fmaxf(t, __shfl_xor(t, 8));
      const float mn = fmaxf(m[r], t);
      float sum = 0.f;
#pragma unroll
      for (int nj = 0; nj < 4; nj++) sum += __expf(acc[nj][r] - mn);
      sum += __shfl_xor(sum, 1);
      sum += __shfl_xor(sum, 2);
      sum += __shfl_xor(sum, 4);
      sum += __shfl_xor(sum, 8);
      l[r] = l[r] * __expf(m[r] - mn) + sum;
      m[r] = mn;
    }
  }

  float invl[4];
#pragma unroll
  for (int r = 0; r < 4; r++) invl[r] = 1.f / l[r];

  fx4 oacc[4];
#pragma unroll
  for (int dj = 0; dj < 4; dj++) oacc[dj] = zero4();

  // ---- sweep 2: P write + PV ----
  for (int kt = 0; kt <= qt; ++kt) {
    fx4 acc[4];
#pragma unroll
    for (int nj = 0; nj < 4; nj++) acc[nj] = zero4();
#pragma unroll
    for (int nj = 0; nj < 4; nj++) {
      const int kcol = kt * 64 + nj * 16 + lo;
      bf16x8 kb0 = *(const bf16x8*)&Kb[(size_t)kcol * KV_DIM + hkv * HD + g * 8];
      bf16x8 kb1 = *(const bf16x8*)&Kb[(size_t)kcol * KV_DIM + hkv * HD + 32 + g * 8];
      acc[nj] = MFMA16(qa0, kb0, acc[nj]);
      acc[nj] = MFMA16(qa1, kb1, acc[nj]);
    }
#pragma unroll
    for (int nj = 0; nj < 4; nj++)
#pragma unroll
      for (int r = 0; r < 4; r++) {
        const int qg = rowb + g * 4 + r;
        const int kg = kt * 64 + nj * 16 + lo;
        float s = acc[nj][r] * 0.125f;
        float p = (kg <= qg) ? __expf(s - m[r]) * invl[r] : 0.f;
        P[((size_t)h * S_LEN + qg) * S_LEN + kg] = p;
        pls[wid][g * 4 + r][nj * 16 + lo] = p;
      }
    // per-wave LDS transpose: p -> MFMA A-fragments (in-wave DS ordering, no barrier)
#pragma unroll
    for (int kk = 0; kk < 2; kk++) {
      float pf[8];
      *(fx4*)&pf[0] = *(const fx4*)&pls[wid][lo][kk * 32 + g * 8];
      *(fx4*)&pf[4] = *(const fx4*)&pls[wid][lo][kk * 32 + g * 8 + 4];
      bf16x8 pa;
#pragma unroll
      for (int i = 0; i < 8; i++) pa[i] = (__bf16)pf[i];
#pragma unroll
      for (int dj = 0; dj < 4; dj++) {
        bf16x8 vb = *(const bf16x8*)&Vt[(size_t)(hkv * HD + dj * 16 + lo) * S_LEN +
                                        kt * 64 + kk * 32 + g * 8];
        oacc[dj] = MFMA16(pa, vb, oacc[dj]);
      }
    }
  }

#pragma unroll
  for (int dj = 0; dj < 4; dj++)
#pragma unroll
    for (int r = 0; r < 4; r++)
      AO[(size_t)(rowb + g * 4 + r) * QH_DIM + h * HD + dj * 16 + lo] = f2bf(oacc[dj][r]);

  // zero-fill strictly-upper (masked) columns so every P element is written each call
  const int zc0 = (qt + 1) * 64;
  const int nzf4 = (S_LEN - zc0) >> 2;
  for (int idx = threadIdx.x; idx < 64 * nzf4; idx += 256) {
    const int r = idx / nzf4;
    const int c = idx - r * nzf4;
    *(fx4*)&P[((size_t)h * S_LEN + qt * 64 + r) * S_LEN + zc0 + c * 4] = zero4();
  }
}

extern "C" void kernel_launch(void* const* d_in, const int* in_sizes, int n_in,
                              void* d_out, int out_size, void* d_ws, size_t ws_size,
                              hipStream_t stream) {
  const float* hs = (const float*)d_in[0];
  const float* cosp = (const float*)d_in[1];
  const float* sinp = (const float*)d_in[2];
  // d_in[3] = attention_mask: pure causal, reconstructed in-kernel
  const float* Wq = (const float*)d_in[4];
  const float* Wk = (const float*)d_in[5];
  const float* Wv = (const float*)d_in[6];
  const float* Wo = (const float*)d_in[7];

  char* w = (char*)d_ws;
  unsigned short* hs_bf = (unsigned short*)w; w += (size_t)S_LEN * 2048 * 2;   // 8 MB
  unsigned short* wq_bf = (unsigned short*)w; w += (size_t)2048 * 2048 * 2;    // 8 MB
  unsigned short* wk_bf = (unsigned short*)w; w += (size_t)512 * 2048 * 2;     // 2 MB
  unsigned short* wv_bf = (unsigned short*)w; w += (size_t)512 * 2048 * 2;     // 2 MB
  unsigned short* wo_bf = (unsigned short*)w; w += (size_t)2048 * 2048 * 2;    // 8 MB
  unsigned short* q_bf  = (unsigned short*)w; w += (size_t)S_LEN * QH_DIM * 2; // 8 MB
  unsigned short* k_bf  = (unsigned short*)w; w += (size_t)S_LEN * KV_DIM * 2; // 2 MB
  unsigned short* v_bf  = (unsigned short*)w; w += (size_t)S_LEN * KV_DIM * 2; // 2 MB
  unsigned short* vt_bf = (unsigned short*)w; w += (size_t)KV_DIM * S_LEN * 2; // 2 MB
  unsigned short* ao_bf = (unsigned short*)w; w += (size_t)S_LEN * QH_DIM * 2; // 8 MB

  float* out0 = (float*)d_out;                      // attn_output [S][2048]
  float* P = out0 + (size_t)S_LEN * QH_DIM;         // attn_weights [32][S][S]

  // 1. casts
  cast_kernel<<<4096, 256, 0, stream>>>(hs, hs_bf, S_LEN * 2048 / 4);
  cast_kernel<<<4096, 256, 0, stream>>>(Wq, wq_bf, 2048 * 2048 / 4);
  cast_kernel<<<1024, 256, 0, stream>>>(Wk, wk_bf, 512 * 2048 / 4);
  cast_kernel<<<1024, 256, 0, stream>>>(Wv, wv_bf, 512 * 2048 / 4);
  cast_kernel<<<4096, 256, 0, stream>>>(Wo, wo_bf, 2048 * 2048 / 4);

  // 2. projections
  gemm_bt<0><<<dim3(16, 16), 256, 0, stream>>>(hs_bf, wq_bf, (void*)q_bf, 2048, 2048, 2048);
  gemm_bt<0><<<dim3(4, 16), 256, 0, stream>>>(hs_bf, wk_bf, (void*)k_bf, 2048, 512, 2048);
  gemm_bt<0><<<dim3(4, 16), 256, 0, stream>>>(hs_bf, wv_bf, (void*)v_bf, 2048, 512, 2048);

  // 3. RoPE + V transpose
  rope_kernel<<<8192, 256, 0, stream>>>(q_bf, cosp, sinp, NH);
  rope_kernel<<<2048, 256, 0, stream>>>(k_bf, cosp, sinp, NKV);
  transpose_v<<<4096, 256, 0, stream>>>(v_bf, vt_bf);

  // 4. fused attention (writes attn_weights fp32 + attn context bf16)
  attn_kernel<<<dim3(NH, 32), 256, 0, stream>>>(q_bf, k_bf, vt_bf, P, ao_bf);

  // 5. output projection (fp32 out)
  gemm_bt<1><<<dim3(16, 16), 256, 0, stream>>>(ao_bf, wo_bf, (void*)out0, 2048, 2048, 2048);
}

// Round 2
// 396.694 us; speedup vs baseline: 1.2512x; 1.2512x over previous
//
#include <hip/hip_runtime.h>

#define S_LEN 2048
#define NH 32
#define NKV 8
#define HD 64
#define QH_DIM (NH * HD)    // 2048
#define QKV_DIM 3072        // 2048 Q + 512 K + 512 V
#define K_OFF 2048
#define V_OFF 2560

typedef __attribute__((ext_vector_type(8))) __bf16 bf16x8;
typedef __attribute__((ext_vector_type(4))) float fx4;

__device__ __forceinline__ unsigned short f2bf(float f) {
  unsigned int u = __builtin_bit_cast(unsigned int, f);
  u = (u + 0x7fffu + ((u >> 16) & 1u)) >> 16;
  return (unsigned short)u;
}
__device__ __forceinline__ float bf2f(unsigned short h) {
  unsigned int u = ((unsigned int)h) << 16;
  return __builtin_bit_cast(float, u);
}
__device__ __forceinline__ fx4 zero4() {
  fx4 z; z[0] = 0.f; z[1] = 0.f; z[2] = 0.f; z[3] = 0.f; return z;
}

#define MFMA16(a, b, c) __builtin_amdgcn_mfma_f32_16x16x32_bf16((a), (b), (c), 0, 0, 0)

// async global -> LDS, 16 bytes per lane (linear dest: wave base + lane*16)
__device__ __forceinline__ void gl16(const void* g, void* l) {
  __builtin_amdgcn_global_load_lds((const __attribute__((address_space(1))) void*)g,
                                   (__attribute__((address_space(3))) void*)l, 16, 0, 0);
}

// ---------------- cast fp32 -> bf16, vectorized ----------------
__global__ __launch_bounds__(256) void cast_kernel(const float* __restrict__ in,
                                                   unsigned short* __restrict__ out, int n4) {
  int i = blockIdx.x * 256 + threadIdx.x;
  if (i >= n4) return;
  float4 v = ((const float4*)in)[i];
  ushort4 o;
  o.x = f2bf(v.x); o.y = f2bf(v.y); o.z = f2bf(v.z); o.w = f2bf(v.w);
  ((ushort4*)out)[i] = o;
}

// ---------------- RoPE in-place on bf16, strided rows ----------------
__global__ __launch_bounds__(256) void rope_kernel(unsigned short* __restrict__ buf,
                                                   const float* __restrict__ cosp,
                                                   const float* __restrict__ sinp, int nheads,
                                                   int rstride) {
  int idx = blockIdx.x * 256 + threadIdx.x;
  int total = S_LEN * nheads * 32;
  if (idx >= total) return;
  int dp = idx & 31;
  int t = idx >> 5;
  int head = t % nheads;
  int s = t / nheads;
  size_t base = (size_t)s * rstride + head * 64;
  float x1 = bf2f(buf[base + dp]);
  float x2 = bf2f(buf[base + dp + 32]);
  float c1 = cosp[s * 64 + dp], s1 = sinp[s * 64 + dp];
  float c2 = cosp[s * 64 + dp + 32], s2 = sinp[s * 64 + dp + 32];
  buf[base + dp] = f2bf(x1 * c1 - x2 * s1);
  buf[base + dp + 32] = f2bf(x2 * c2 + x1 * s2);
}

// ---------------- V (strided rows) -> Vt [512][S] ----------------
__global__ __launch_bounds__(256) void transpose_v(const unsigned short* __restrict__ V,
                                                   unsigned short* __restrict__ Vt, int rstride) {
  int idx = blockIdx.x * 256 + threadIdx.x;  // 512*2048 total
  int c = idx >> 11;                         // 0..511
  int r = idx & 2047;                        // 0..2047
  Vt[((size_t)c << 11) + r] = V[(size_t)r * rstride + c];
}

// ---------------- GEMM: C[M][N] = A[M][K] * B[N][K]^T (bf16 in) ----------------
// 128x128 tile, BK=32, 4 waves, m97-style global_load_lds staging.
template <int F32OUT>
__global__ __launch_bounds__(256) void gemm_bt(const unsigned short* __restrict__ A,
                                               const unsigned short* __restrict__ B,
                                               void* __restrict__ C, int M, int N, int K) {
  __shared__ unsigned short As[128 * 32];
  __shared__ unsigned short Bs[128 * 32];
  const int tid = threadIdx.x;
  const int bn = blockIdx.x * 128, bm = blockIdx.y * 128;
  const int lane = tid & 63, wid = tid >> 6;
  const int lo = lane & 15, g = lane >> 4;
  const int wr = wid >> 1, wc = wid & 1;

  fx4 acc[4][4];
#pragma unroll
  for (int i = 0; i < 4; i++)
#pragma unroll
    for (int j = 0; j < 4; j++) acc[i][j] = zero4();

  const int r0 = tid >> 2, sg = tid & 3;  // thread's staging row/16B-segment
  const unsigned short* ap0 = &A[(size_t)(bm + r0) * K + sg * 8];
  const unsigned short* ap1 = &A[(size_t)(bm + 64 + r0) * K + sg * 8];
  const unsigned short* bp0 = &B[(size_t)(bn + r0) * K + sg * 8];
  const unsigned short* bp1 = &B[(size_t)(bn + 64 + r0) * K + sg * 8];
  // LDS linear layout: row*32 + col  ==  tid*8 for (r0, sg*8)
  unsigned short* asl0 = &As[(size_t)tid * 8];
  unsigned short* asl1 = &As[(size_t)tid * 8 + 2048];
  unsigned short* bsl0 = &Bs[(size_t)tid * 8];
  unsigned short* bsl1 = &Bs[(size_t)tid * 8 + 2048];

  for (int k0 = 0; k0 < K; k0 += 32) {
    __syncthreads();  // previous iteration's LDS reads done
    gl16(ap0 + k0, asl0);
    gl16(ap1 + k0, asl1);
    gl16(bp0 + k0, bsl0);
    gl16(bp1 + k0, bsl1);
    __syncthreads();  // vmcnt(0) drain -> staged data visible
    bf16x8 af[4], bb[4];
#pragma unroll
    for (int mi = 0; mi < 4; mi++)
      af[mi] = *(const bf16x8*)&As[(wr * 64 + mi * 16 + lo) * 32 + g * 8];
#pragma unroll
    for (int nj = 0; nj < 4; nj++)
      bb[nj] = *(const bf16x8*)&Bs[(wc * 64 + nj * 16 + lo) * 32 + g * 8];
#pragma unroll
    for (int mi = 0; mi < 4; mi++)
#pragma unroll
      for (int nj = 0; nj < 4; nj++) acc[mi][nj] = MFMA16(af[mi], bb[nj], acc[mi][nj]);
  }

#pragma unroll
  for (int mi = 0; mi < 4; mi++)
#pragma unroll
    for (int nj = 0; nj < 4; nj++)
#pragma unroll
      for (int r = 0; r < 4; r++) {
        int row = bm + wr * 64 + mi * 16 + g * 4 + r;
        int col = bn + wc * 64 + nj * 16 + lo;
        if (F32OUT)
          ((float*)C)[(size_t)row * N + col] = acc[mi][nj][r];
        else
          ((unsigned short*)C)[(size_t)row * N + col] = f2bf(acc[mi][nj][r]);
      }
}

// ---------------- fused causal attention ----------------
// grid (NH, 32 qtiles); 4 waves; each wave owns 16 q-rows.
// Two sweeps over k-tiles: (1) online m,l  (2) write P fp32 + PV accumulate.
__global__ __launch_bounds__(256) void attn_kernel(const unsigned short* __restrict__ Q,
                                                   const unsigned short* __restrict__ Kb,
                                                   const unsigned short* __restrict__ Vt,
                                                   float* __restrict__ P,
                                                   unsigned short* __restrict__ AO) {
  __shared__ float pls[4][16][84];  // per-wave P staging; 84-stride: conflict-free
  const int h = blockIdx.x;
  const int qt = 31 - blockIdx.y;  // heavy (large qt) blocks dispatch first
  const int hkv = h >> 2;
  const int wid = threadIdx.x >> 6, lane = threadIdx.x & 63;
  const int lo = lane & 15, g = lane >> 4;
  const int rowb = qt * 64 + wid * 16;

  const bf16x8 qa0 = *(const bf16x8*)&Q[(size_t)(rowb + lo) * QKV_DIM + h * HD + g * 8];
  const bf16x8 qa1 = *(const bf16x8*)&Q[(size_t)(rowb + lo) * QKV_DIM + h * HD + 32 + g * 8];

  float m[4], l[4];
#pragma unroll
  for (int r = 0; r < 4; r++) { m[r] = -1e30f; l[r] = 0.f; }

  // ---- sweep 1: running max/denominator ----
  for (int kt = 0; kt <= qt; ++kt) {
    fx4 acc[4];
#pragma unroll
    for (int nj = 0; nj < 4; nj++) acc[nj] = zero4();
#pragma unroll
    for (int nj = 0; nj < 4; nj++) {
      const int kcol = kt * 64 + nj * 16 + lo;
      bf16x8 kb0 = *(const bf16x8*)&Kb[(size_t)kcol * QKV_DIM + hkv * HD + g * 8];
      bf16x8 kb1 = *(const bf16x8*)&Kb[(size_t)kcol * QKV_DIM + hkv * HD + 32 + g * 8];
      acc[nj] = MFMA16(qa0, kb0, acc[nj]);
      acc[nj] = MFMA16(qa1, kb1, acc[nj]);
    }
    float tmax[4];
#pragma unroll
    for (int r = 0; r < 4; r++) tmax[r] = -1e30f;
#pragma unroll
    for (int nj = 0; nj < 4; nj++)
#pragma unroll
      for (int r = 0; r < 4; r++) {
        const int qg = rowb + g * 4 + r;
        const int kg = kt * 64 + nj * 16 + lo;
        float s = acc[nj][r] * 0.125f;
        if (kg > qg) s = -1e9f;
        acc[nj][r] = s;
        tmax[r] = fmaxf(tmax[r], s);
      }
#pragma unroll
    for (int r = 0; r < 4; r++) {
      float t = tmax[r];
      t = fmaxf(t, __shfl_xor(t, 1));
      t = fmaxf(t, __shfl_xor(t, 2));
      t = fmaxf(t, __shfl_xor(t, 4));
      t = fmaxf(t, __shfl_xor(t, 8));
      const float mn = fmaxf(m[r], t);
      float sum = 0.f;
#pragma unroll
      for (int nj = 0; nj < 4; nj++) sum += __expf(acc[nj][r] - mn);
      sum += __shfl_xor(sum, 1);
      sum += __shfl_xor(sum, 2);
      sum += __shfl_xor(sum, 4);
      sum += __shfl_xor(sum, 8);
      l[r] = l[r] * __expf(m[r] - mn) + sum;
      m[r] = mn;
    }
  }

  float invl[4];
#pragma unroll
  for (int r = 0; r < 4; r++) invl[r] = 1.f / l[r];

  fx4 oacc[4];
#pragma unroll
  for (int dj = 0; dj < 4; dj++) oacc[dj] = zero4();

  // ---- sweep 2: P write + PV ----
  for (int kt = 0; kt <= qt; ++kt) {
    fx4 acc[4];
#pragma unroll
    for (int nj = 0; nj < 4; nj++) acc[nj] = zero4();
#pragma unroll
    for (int nj = 0; nj < 4; nj++) {
      const int kcol = kt * 64 + nj * 16 + lo;
      bf16x8 kb0 = *(const bf16x8*)&Kb[(size_t)kcol * QKV_DIM + hkv * HD + g * 8];
      bf16x8 kb1 = *(const bf16x8*)&Kb[(size_t)kcol * QKV_DIM + hkv * HD + 32 + g * 8];
      acc[nj] = MFMA16(qa0, kb0, acc[nj]);
      acc[nj] = MFMA16(qa1, kb1, acc[nj]);
    }
#pragma unroll
    for (int nj = 0; nj < 4; nj++)
#pragma unroll
      for (int r = 0; r < 4; r++) {
        const int qg = rowb + g * 4 + r;
        const int kg = kt * 64 + nj * 16 + lo;
        float s = acc[nj][r] * 0.125f;
        float p = (kg <= qg) ? __expf(s - m[r]) * invl[r] : 0.f;
        pls[wid][g * 4 + r][nj * 16 + lo] = p;
      }
    // vectorized P write: 16 rows x 64 cols as fx4, 256B-contiguous per 16 lanes
#pragma unroll
    for (int it = 0; it < 4; it++) {
      const int row = (lane >> 4) + it * 4;
      const int ch = lane & 15;
      fx4 pv = *(const fx4*)&pls[wid][row][ch * 4];
      *(fx4*)&P[((size_t)h * S_LEN + rowb + row) * S_LEN + kt * 64 + ch * 4] = pv;
    }
    // per-wave LDS transpose: p -> MFMA A-fragments (in-wave DS ordering, no barrier)
#pragma unroll
    for (int kk = 0; kk < 2; kk++) {
      float pf[8];
      *(fx4*)&pf[0] = *(const fx4*)&pls[wid][lo][kk * 32 + g * 8];
      *(fx4*)&pf[4] = *(const fx4*)&pls[wid][lo][kk * 32 + g * 8 + 4];
      bf16x8 pa;
#pragma unroll
      for (int i = 0; i < 8; i++) pa[i] = (__bf16)pf[i];
#pragma unroll
      for (int dj = 0; dj < 4; dj++) {
        bf16x8 vb = *(const bf16x8*)&Vt[(size_t)(hkv * HD + dj * 16 + lo) * S_LEN +
                                        kt * 64 + kk * 32 + g * 8];
        oacc[dj] = MFMA16(pa, vb, oacc[dj]);
      }
    }
  }

#pragma unroll
  for (int dj = 0; dj < 4; dj++)
#pragma unroll
    for (int r = 0; r < 4; r++)
      AO[(size_t)(rowb + g * 4 + r) * QH_DIM + h * HD + dj * 16 + lo] = f2bf(oacc[dj][r]);

  // zero-fill strictly-upper (masked) columns so every P element is written each call
  const int zc0 = (qt + 1) * 64;
  const int nzf4 = (S_LEN - zc0) >> 2;
  for (int idx = threadIdx.x; idx < 64 * nzf4; idx += 256) {
    const int r = idx / nzf4;
    const int c = idx - r * nzf4;
    *(fx4*)&P[((size_t)h * S_LEN + qt * 64 + r) * S_LEN + zc0 + c * 4] = zero4();
  }
}

extern "C" void kernel_launch(void* const* d_in, const int* in_sizes, int n_in,
                              void* d_out, int out_size, void* d_ws, size_t ws_size,
                              hipStream_t stream) {
  const float* hs = (const float*)d_in[0];
  const float* cosp = (const float*)d_in[1];
  const float* sinp = (const float*)d_in[2];
  // d_in[3] = attention_mask: pure causal, reconstructed in-kernel
  const float* Wq = (const float*)d_in[4];
  const float* Wk = (const float*)d_in[5];
  const float* Wv = (const float*)d_in[6];
  const float* Wo = (const float*)d_in[7];

  char* w = (char*)d_ws;
  unsigned short* hs_bf   = (unsigned short*)w; w += (size_t)S_LEN * 2048 * 2;    // 8 MB
  unsigned short* wqkv_bf = (unsigned short*)w; w += (size_t)QKV_DIM * 2048 * 2;  // 12 MB
  unsigned short* wo_bf   = (unsigned short*)w; w += (size_t)2048 * 2048 * 2;     // 8 MB
  unsigned short* qkv_bf  = (unsigned short*)w; w += (size_t)S_LEN * QKV_DIM * 2; // 12 MB
  unsigned short* vt_bf   = (unsigned short*)w; w += (size_t)512 * S_LEN * 2;     // 2 MB
  unsigned short* ao_bf   = (unsigned short*)w; w += (size_t)S_LEN * QH_DIM * 2;  // 8 MB

  float* out0 = (float*)d_out;               // attn_output [S][2048]
  float* P = out0 + (size_t)S_LEN * QH_DIM;  // attn_weights [32][S][S]

  // 1. casts (Wq/Wk/Wv stacked into one [3072][2048] bf16 B matrix)
  cast_kernel<<<4096, 256, 0, stream>>>(hs, hs_bf, S_LEN * 2048 / 4);
  cast_kernel<<<4096, 256, 0, stream>>>(Wq, wqkv_bf, 2048 * 2048 / 4);
  cast_kernel<<<1024, 256, 0, stream>>>(Wk, wqkv_bf + (size_t)K_OFF * 2048, 512 * 2048 / 4);
  cast_kernel<<<1024, 256, 0, stream>>>(Wv, wqkv_bf + (size_t)V_OFF * 2048, 512 * 2048 / 4);
  cast_kernel<<<4096, 256, 0, stream>>>(Wo, wo_bf, 2048 * 2048 / 4);

  // 2. fused QKV projection: qkv[2048][3072]
  gemm_bt<0><<<dim3(QKV_DIM / 128, 16), 256, 0, stream>>>(hs_bf, wqkv_bf, (void*)qkv_bf,
                                                          2048, QKV_DIM, 2048);

  // 3. RoPE on Q,K views + V transpose
  rope_kernel<<<8192, 256, 0, stream>>>(qkv_bf, cosp, sinp, NH, QKV_DIM);
  rope_kernel<<<2048, 256, 0, stream>>>(qkv_bf + K_OFF, cosp, sinp, NKV, QKV_DIM);
  transpose_v<<<4096, 256, 0, stream>>>(qkv_bf + V_OFF, vt_bf, QKV_DIM);

  // 4. fused attention (writes attn_weights fp32 + attn context bf16)
  attn_kernel<<<dim3(NH, 32), 256, 0, stream>>>(qkv_bf, qkv_bf + K_OFF, vt_bf, P, ao_bf);

  // 5. output projection (fp32 out)
  gemm_bt<1><<<dim3(16, 16), 256, 0, stream>>>(ao_bf, wo_bf, (void*)out0, 2048, 2048, 2048);
}